// Round 3
// baseline (405.439 us; speedup 1.0000x reference)
//
#include <hip/hip_runtime.h>
#include <stdint.h>

// out[b,m,f] = sum_n x[b,n,f] * (support[n,m]*kernel[n,m]) + bias[f]
// support is a k-hop ring mask -> EXACTLY 7 nonzeros per column (incl. wrap
// columns). Strategy:
//   1) build_csc_kernel: compact W columns into (cnt, idx, val) in d_ws
//   2) spmm7_kernel: 1 block per (b,m); thread t owns one float4 f-slice.
//      All metadata loads (cnt, ip[0..6], vp[0..6]) issue IN PARALLEL, then
//      the 7-tap x gather is fully unrolled -> one vmcnt wait instead of
//      seven chained ones. 50944 blocks give the TLP that hides L3/HBM
//      latency (round-2 lesson: strip-mining killed exactly this).
//      XCD swizzle keeps one batch's m-blocks on one XCD: the batch's x slab
//      (199 rows x 4KB = 815 KB) fits that XCD's 4 MB L2 -> 7x reuse is
//      L2-local. Generic gather path covers any c != 7 support.

typedef float nt_f4 __attribute__((ext_vector_type(4)));  // native vec for nontemporal builtin

__device__ __forceinline__ void nt_store4(const float4& a, float4* p) {
    nt_f4 v;
    v.x = a.x; v.y = a.y; v.z = a.z; v.w = a.w;
    __builtin_nontemporal_store(v, (nt_f4*)p);
}

__global__ void build_csc_kernel(const float* __restrict__ support,
                                 const float* __restrict__ kern,
                                 int* __restrict__ cnt,
                                 int* __restrict__ idx,
                                 float* __restrict__ val,
                                 int n) {
    const int m = blockIdx.x;      // one column per block
    const int lane = threadIdx.x;  // 64 threads = one wave
    int base = 0;
    for (int n0 = 0; n0 < n; n0 += 64) {
        const int row = n0 + lane;
        float w = 0.0f;
        if (row < n) w = support[(size_t)row * n + m] * kern[(size_t)row * n + m];
        const unsigned long long mask = __ballot(w != 0.0f);
        const int pos = base + (int)__popcll(mask & ((1ull << lane) - 1ull));
        if (w != 0.0f) {
            idx[(size_t)m * n + pos] = row;   // ascending row order
            val[(size_t)m * n + pos] = w;
        }
        base += (int)__popcll(mask);
    }
    if (lane == 0) cnt[m] = base;
}

__global__ __launch_bounds__(256) void spmm7_kernel(
    const float4* __restrict__ x, const float* __restrict__ bias,
    const int* __restrict__ cnt, const int* __restrict__ idx,
    const float* __restrict__ val, float4* __restrict__ out,
    int n, int f4, int swizzle) {
    const int blk = blockIdx.x;
    int b, m;
    if (swizzle) {
        // all m-blocks of one batch b land on one XCD, consecutively
        const int xcd = blk & 7;
        const int ii = blk >> 3;
        b = xcd + 8 * (ii / n);
        m = ii % n;
    } else {
        b = blk / n;
        m = blk % n;
    }
    const int* __restrict__ ip = idx + (size_t)m * n;
    const float* __restrict__ vp = val + (size_t)m * n;

    // Metadata: all 15 loads independent -> single latency level.
    // ip/vp slots are n entries per column, so j=0..6 are always in-bounds;
    // values past cnt are garbage but only USED when c == 7.
    const int c = cnt[m];
    const int i0 = ip[0], i1 = ip[1], i2 = ip[2], i3 = ip[3];
    const int i4 = ip[4], i5 = ip[5], i6 = ip[6];
    const float w0 = vp[0], w1 = vp[1], w2 = vp[2], w3 = vp[3];
    const float w4 = vp[4], w5 = vp[5], w6 = vp[6];

    const float4* __restrict__ b4 = (const float4*)bias;
    const size_t xbase = (size_t)b * n * f4;
    const size_t obase = ((size_t)b * n + m) * f4;

    for (int t = threadIdx.x; t < f4; t += 256) {
        float4 acc = b4[t];
        if (c == 7) {
            // 7 independent loads issue back-to-back: ONE wait, not seven.
            const float4 v0 = x[xbase + (size_t)i0 * f4 + t];
            const float4 v1 = x[xbase + (size_t)i1 * f4 + t];
            const float4 v2 = x[xbase + (size_t)i2 * f4 + t];
            const float4 v3 = x[xbase + (size_t)i3 * f4 + t];
            const float4 v4 = x[xbase + (size_t)i4 * f4 + t];
            const float4 v5 = x[xbase + (size_t)i5 * f4 + t];
            const float4 v6 = x[xbase + (size_t)i6 * f4 + t];
            // ascending-row order == reference accumulation order
            acc.x = fmaf(w0, v0.x, acc.x); acc.y = fmaf(w0, v0.y, acc.y);
            acc.z = fmaf(w0, v0.z, acc.z); acc.w = fmaf(w0, v0.w, acc.w);
            acc.x = fmaf(w1, v1.x, acc.x); acc.y = fmaf(w1, v1.y, acc.y);
            acc.z = fmaf(w1, v1.z, acc.z); acc.w = fmaf(w1, v1.w, acc.w);
            acc.x = fmaf(w2, v2.x, acc.x); acc.y = fmaf(w2, v2.y, acc.y);
            acc.z = fmaf(w2, v2.z, acc.z); acc.w = fmaf(w2, v2.w, acc.w);
            acc.x = fmaf(w3, v3.x, acc.x); acc.y = fmaf(w3, v3.y, acc.y);
            acc.z = fmaf(w3, v3.z, acc.z); acc.w = fmaf(w3, v3.w, acc.w);
            acc.x = fmaf(w4, v4.x, acc.x); acc.y = fmaf(w4, v4.y, acc.y);
            acc.z = fmaf(w4, v4.z, acc.z); acc.w = fmaf(w4, v4.w, acc.w);
            acc.x = fmaf(w5, v5.x, acc.x); acc.y = fmaf(w5, v5.y, acc.y);
            acc.z = fmaf(w5, v5.z, acc.z); acc.w = fmaf(w5, v5.w, acc.w);
            acc.x = fmaf(w6, v6.x, acc.x); acc.y = fmaf(w6, v6.y, acc.y);
            acc.z = fmaf(w6, v6.z, acc.z); acc.w = fmaf(w6, v6.w, acc.w);
        } else {
            // generic gather (arbitrary support)
            for (int j = 0; j < c; ++j) {
                const int nn = ip[j];
                const float w = vp[j];
                const float4 v = x[xbase + (size_t)nn * f4 + t];
                acc.x = fmaf(w, v.x, acc.x);
                acc.y = fmaf(w, v.y, acc.y);
                acc.z = fmaf(w, v.z, acc.z);
                acc.w = fmaf(w, v.w, acc.w);
            }
        }
        nt_store4(acc, &out[obase + t]);
    }
}

// Correctness fallback if d_ws is too small for the CSC arrays (unlikely).
__global__ __launch_bounds__(256) void dense_fallback_kernel(
    const float4* __restrict__ x, const float* __restrict__ support,
    const float* __restrict__ kern, const float* __restrict__ bias,
    float4* __restrict__ out, int n, int f4) {
    const int blk = blockIdx.x;
    const int b = blk / n;
    const int m = blk % n;
    const float4* __restrict__ b4 = (const float4*)bias;
    const size_t xbase = (size_t)b * n * f4;
    const size_t obase = ((size_t)b * n + m) * f4;
    for (int t = threadIdx.x; t < f4; t += 256) {
        float4 acc = b4[t];
        for (int nn = 0; nn < n; ++nn) {
            const float w = support[(size_t)nn * n + m] * kern[(size_t)nn * n + m];
            if (w != 0.0f) {
                const float4 v = x[xbase + (size_t)nn * f4 + t];
                acc.x = fmaf(w, v.x, acc.x);
                acc.y = fmaf(w, v.y, acc.y);
                acc.z = fmaf(w, v.z, acc.z);
                acc.w = fmaf(w, v.w, acc.w);
            }
        }
        out[obase + t] = acc;
    }
}

extern "C" void kernel_launch(void* const* d_in, const int* in_sizes, int n_in,
                              void* d_out, int out_size, void* d_ws, size_t ws_size,
                              hipStream_t stream) {
    const float* x       = (const float*)d_in[0];
    const float* support = (const float*)d_in[1];
    const float* kern    = (const float*)d_in[2];
    const float* bias    = (const float*)d_in[3];
    float* out = (float*)d_out;

    // n from support (n*n elements); f from bias; batch from x.
    const int nsq = in_sizes[1];
    int n = 1;
    while (n * n < nsq) ++n;          // n = 199
    const int f = in_sizes[3];        // 1024
    const int f4 = f / 4;             // 256
    const int batch = in_sizes[0] / (n * f);  // 256

    const size_t need = ((size_t)n + 2u * (size_t)n * (size_t)n) * 4u;
    if (ws_size >= need && (f % 4) == 0 && n >= 7) {
        int* cnt = (int*)d_ws;
        int* idx = cnt + n;
        float* val = (float*)(idx + (size_t)n * n);
        build_csc_kernel<<<n, 64, 0, stream>>>(support, kern, cnt, idx, val, n);
        const int swz = (batch % 8 == 0) ? 1 : 0;
        spmm7_kernel<<<batch * n, 256, 0, stream>>>(
            (const float4*)x, bias, cnt, idx, val, (float4*)out, n, f4, swz);
    } else {
        dense_fallback_kernel<<<batch * n, 256, 0, stream>>>(
            (const float4*)x, support, kern, bias, (float4*)out, n, f / 4);
    }
}

// Round 4
// 354.473 us; speedup vs baseline: 1.1438x; 1.1438x over previous
//
#include <hip/hip_runtime.h>
#include <stdint.h>

// out[b,m,f] = sum_n x[b,n,f] * (support[n,m]*kernel[n,m]) + bias[f]
// support is a k-hop ring mask -> 7 nonzeros per column at rows
// (m-3..m+3) mod n. Strategy:
//   1) build_csc_kernel: compact W columns into (cnt, idx, val)   [generic]
//   2) build_band_kernel: dense band table wband[m][j] = W[(m-3+j)%n][m]
//      plus per-column fastok flag (VERIFIED: all nonzeros inside band,
//      interior column so ascending-row accumulation order is preserved).
//   3) spmm_band4_kernel: block = (b, 4 consecutive columns). Thread t owns
//      one float4 f-slice; loads the 10 shared window rows ONCE (all
//      independent -> single latency level), then 4 x 7 FMA4 + 4 plain
//      stores. 2.5 x-loads per output vs 7 in the per-(b,m) gather version;
//      L1/L2 read amplification drops 7x -> 2.5x. NO nontemporal stores
//      (rounds 2/3 showed nt-store regressed 128 -> 144/164 us at identical
//      traffic). Wrap/non-band columns fall back to the CSC gather inline.
//      XCD swizzle keeps one batch's column-groups on one XCD (x slab 815KB
//      fits the 4MB XCD L2 -> halo re-reads are L2-local).

#define CPB 4  // columns per block (window = CPB+6 rows)

__global__ void build_csc_kernel(const float* __restrict__ support,
                                 const float* __restrict__ kern,
                                 int* __restrict__ cnt,
                                 int* __restrict__ idx,
                                 float* __restrict__ val,
                                 int n) {
    const int m = blockIdx.x;      // one column per block
    const int lane = threadIdx.x;  // 64 threads = one wave
    int base = 0;
    for (int n0 = 0; n0 < n; n0 += 64) {
        const int row = n0 + lane;
        float w = 0.0f;
        if (row < n) w = support[(size_t)row * n + m] * kern[(size_t)row * n + m];
        const unsigned long long mask = __ballot(w != 0.0f);
        const int pos = base + (int)__popcll(mask & ((1ull << lane) - 1ull));
        if (w != 0.0f) {
            idx[(size_t)m * n + pos] = row;   // ascending row order
            val[(size_t)m * n + pos] = w;
        }
        base += (int)__popcll(mask);
    }
    if (lane == 0) cnt[m] = base;
}

// wband[m*8+j] = W[(m-3+j) mod n][m]; fastok[m] = 1 iff every nonzero of
// column m lies inside the band AND m is interior (so band j-order ==
// ascending row order == reference accumulation order).
__global__ void build_band_kernel(const float* __restrict__ support,
                                  const float* __restrict__ kern,
                                  const int* __restrict__ cnt,
                                  float* __restrict__ wband,
                                  int* __restrict__ fastok,
                                  int n) {
    const int m = blockIdx.x * blockDim.x + threadIdx.x;
    if (m >= n) return;
    int cb = 0;
    for (int j = 0; j < 7; ++j) {
        int r = m - 3 + j;
        if (r < 0) r += n;
        if (r >= n) r -= n;
        const float w = support[(size_t)r * n + m] * kern[(size_t)r * n + m];
        wband[(size_t)m * 8 + j] = w;
        cb += (w != 0.0f) ? 1 : 0;
    }
    wband[(size_t)m * 8 + 7] = 0.0f;
    fastok[m] = (n >= 7 && cb == cnt[m] && m >= 3 && m <= n - 4) ? 1 : 0;
}

__global__ __launch_bounds__(256) void spmm_band4_kernel(
    const float4* __restrict__ x, const float* __restrict__ bias,
    const int* __restrict__ cnt, const int* __restrict__ idx,
    const float* __restrict__ val, const float* __restrict__ wband,
    const int* __restrict__ fastok, float4* __restrict__ out,
    int n, int f4, int ngroups, int swizzle) {
    const int blk = blockIdx.x;
    int b, g;
    if (swizzle) {
        // all column-groups of one batch b land on one XCD, consecutively
        const int xcd = blk & 7;
        const int ii = blk >> 3;
        g = ii % ngroups;
        b = xcd + 8 * (ii / ngroups);
    } else {
        b = blk / ngroups;
        g = blk % ngroups;
    }
    const int m0 = g * CPB;
    const float4* __restrict__ xb = x + (size_t)b * n * f4;
    float4* __restrict__ ob = out + (size_t)b * n * f4;
    const float4* __restrict__ b4 = (const float4*)bias;

    for (int t = threadIdx.x; t < f4; t += 256) {
        const float4 bias4 = b4[t];
        // shared window rows m0-3 .. m0+CPB+2, clamped (clamped rows are only
        // loaded, never used: columns needing them take the generic path)
        float4 win[CPB + 6];
#pragma unroll
        for (int j = 0; j < CPB + 6; ++j) {
            int r = m0 - 3 + j;
            r = (r < 0) ? 0 : ((r >= n) ? (n - 1) : r);
            win[j] = xb[(size_t)r * f4 + t];
        }
#pragma unroll
        for (int dm = 0; dm < CPB; ++dm) {
            const int m = m0 + dm;
            if (m >= n) break;
            float4 a = bias4;
            if (fastok[m]) {
                const float* __restrict__ wb = wband + (size_t)m * 8;
#pragma unroll
                for (int j = 0; j < 7; ++j) {
                    const float w = wb[j];  // ascending-row order (interior)
                    a.x = fmaf(w, win[dm + j].x, a.x);
                    a.y = fmaf(w, win[dm + j].y, a.y);
                    a.z = fmaf(w, win[dm + j].z, a.z);
                    a.w = fmaf(w, win[dm + j].w, a.w);
                }
            } else {
                // generic CSC gather (wrap columns, arbitrary support)
                const int c = cnt[m];
                const int* __restrict__ ip = idx + (size_t)m * n;
                const float* __restrict__ vp = val + (size_t)m * n;
                for (int j = 0; j < c; ++j) {
                    const int nn = ip[j];
                    const float w = vp[j];
                    const float4 v = xb[(size_t)nn * f4 + t];
                    a.x = fmaf(w, v.x, a.x);
                    a.y = fmaf(w, v.y, a.y);
                    a.z = fmaf(w, v.z, a.z);
                    a.w = fmaf(w, v.w, a.w);
                }
            }
            ob[(size_t)m * f4 + t] = a;  // plain store (nt regressed)
        }
    }
}

// Correctness fallback if d_ws is too small for the CSC arrays (unlikely).
__global__ __launch_bounds__(256) void dense_fallback_kernel(
    const float4* __restrict__ x, const float* __restrict__ support,
    const float* __restrict__ kern, const float* __restrict__ bias,
    float4* __restrict__ out, int n, int f4) {
    const int blk = blockIdx.x;
    const int b = blk / n;
    const int m = blk % n;
    const float4* __restrict__ b4 = (const float4*)bias;
    const size_t xbase = (size_t)b * n * f4;
    const size_t obase = ((size_t)b * n + m) * f4;
    for (int t = threadIdx.x; t < f4; t += 256) {
        float4 acc = b4[t];
        for (int nn = 0; nn < n; ++nn) {
            const float w = support[(size_t)nn * n + m] * kern[(size_t)nn * n + m];
            if (w != 0.0f) {
                const float4 v = x[xbase + (size_t)nn * f4 + t];
                acc.x = fmaf(w, v.x, acc.x);
                acc.y = fmaf(w, v.y, acc.y);
                acc.z = fmaf(w, v.z, acc.z);
                acc.w = fmaf(w, v.w, acc.w);
            }
        }
        out[obase + t] = acc;
    }
}

extern "C" void kernel_launch(void* const* d_in, const int* in_sizes, int n_in,
                              void* d_out, int out_size, void* d_ws, size_t ws_size,
                              hipStream_t stream) {
    const float* x       = (const float*)d_in[0];
    const float* support = (const float*)d_in[1];
    const float* kern    = (const float*)d_in[2];
    const float* bias    = (const float*)d_in[3];
    float* out = (float*)d_out;

    // n from support (n*n elements); f from bias; batch from x.
    const int nsq = in_sizes[1];
    int n = 1;
    while (n * n < nsq) ++n;          // n = 199
    const int f = in_sizes[3];        // 1024
    const int f4 = f / 4;             // 256
    const int batch = in_sizes[0] / (n * f);  // 256

    // ws layout: cnt[n] | idx[n*n] | val[n*n] | wband[8n] | fastok[n]
    const size_t need = ((size_t)2 * n * n + 10u * (size_t)n) * 4u;
    if (ws_size >= need && (f % 4) == 0 && n >= 7) {
        int* cnt = (int*)d_ws;
        int* idx = cnt + n;
        float* val = (float*)(idx + (size_t)n * n);
        float* wband = val + (size_t)n * n;
        int* fastok = (int*)(wband + (size_t)8 * n);
        build_csc_kernel<<<n, 64, 0, stream>>>(support, kern, cnt, idx, val, n);
        build_band_kernel<<<(n + 255) / 256, 256, 0, stream>>>(
            support, kern, cnt, wband, fastok, n);
        const int ngroups = (n + CPB - 1) / CPB;  // 50
        const int swz = (batch % 8 == 0) ? 1 : 0;
        spmm_band4_kernel<<<batch * ngroups, 256, 0, stream>>>(
            (const float4*)x, bias, cnt, idx, val, wband, fastok,
            (float4*)out, n, f4, ngroups, swz);
    } else {
        dense_fallback_kernel<<<batch * n, 256, 0, stream>>>(
            (const float4*)x, support, kern, bias, (float4*)out, n, f / 4);
    }
}